// Round 6
// baseline (112.231 us; speedup 1.0000x reference)
//
#include <hip/hip_runtime.h>

// Gaussian 3x3 conv forward, B=64, C=1, H=W=512, N_MULT=1.
// taps = max(rint(clamp(w,0.001,0.999)*clamp(wf,1.001,254.999)), 0.001), then
// 3x3 conv, zero padding=1. Output [1,64,1,512,512] fp32 (flat layout == input).
//
// Full-row wave mapping (one wave64 == one 512-float row; lane holds
// row4[lane] and row4[lane+64]); all horizontal halos via shuffles, zero
// fix-up loads. This round: ALL 12 row-loads hoisted into arrays and issued
// back-to-back before any compute (single vmcnt region, max MLP per wave);
// interior rows j=1..RR are unconditionally in-image (no branch).

#define BB 64
#define HH 512
#define WW 512
#define RR 4          // output rows per thread

typedef float vfloat4 __attribute__((ext_vector_type(4)));

__global__ __launch_bounds__(256) void gauss3x3_kernel(
    const float* __restrict__ in,     // [B,1,H,W]
    const float* __restrict__ wgt,    // [1,9]
    const float* __restrict__ wfac,   // [1,1]
    float* __restrict__ out)          // [1,B,1,H,W]
{
    // Derive the 9 taps (redundant per thread; scalar broadcast loads).
    float wf = fminf(fmaxf(wfac[0], 1.001f), 254.999f);
    float k[9];
#pragma unroll
    for (int i = 0; i < 9; ++i) {
        float wc = fminf(fmaxf(wgt[i], 0.001f), 0.999f);
        k[i] = fmaxf(rintf(wc * wf), 0.001f);   // rintf = round-half-even = jnp.round
    }

    const int gtid  = blockIdx.x * blockDim.x + threadIdx.x;
    const int lane  = threadIdx.x & 63;
    const int wid   = gtid >> 6;                 // wave id: [0, BB*HH/RR)
    const int strip = wid & (HH / RR - 1);       // wave-uniform: 4-row strip
    const int b     = wid >> 7;                  // wave-uniform: batch (HH/RR=128)
    if (b >= BB) return;

    const int y0 = strip * RR;
    const float* img  = in  + (size_t)b * HH * WW;
    float*       outp = out + (size_t)b * HH * WW;

    // ---- Phase 1: issue ALL loads back-to-back (6 rows x 2 dwordx4) ----
    float4 c1[RR + 2], c2[RR + 2];
    {   // top halo row (out of image only for strip 0)
        const int ry = y0 - 1;
        if (ry >= 0) {
            const float4* row4 = (const float4*)(img + (size_t)ry * WW);
            c1[0] = row4[lane];  c2[0] = row4[lane + 64];
        } else {
            c1[0] = make_float4(0.f, 0.f, 0.f, 0.f);  c2[0] = c1[0];
        }
    }
#pragma unroll
    for (int j = 1; j <= RR; ++j) {              // always in-image
        const float4* row4 = (const float4*)(img + (size_t)(y0 - 1 + j) * WW);
        c1[j] = row4[lane];  c2[j] = row4[lane + 64];
    }
    {   // bottom halo row (out of image only for last strip)
        const int ry = y0 + RR;
        if (ry < HH) {
            const float4* row4 = (const float4*)(img + (size_t)ry * WW);
            c1[RR + 1] = row4[lane];  c2[RR + 1] = row4[lane + 64];
        } else {
            c1[RR + 1] = make_float4(0.f, 0.f, 0.f, 0.f);  c2[RR + 1] = c1[RR + 1];
        }
    }

    // ---- Phase 2: compute ----
    float4 acc1[RR], acc2[RR];
#pragma unroll
    for (int i = 0; i < RR; ++i) {
        acc1[i] = make_float4(0.f, 0.f, 0.f, 0.f);
        acc2[i] = make_float4(0.f, 0.f, 0.f, 0.f);
    }

#pragma unroll
    for (int j = 0; j < RR + 2; ++j) {
        // Horizontal halos — all in-register (wave edges == image edges):
        float l1n = __shfl_up(c1[j].w, 1);
        float r1n = __shfl_down(c1[j].x, 1);
        float l2n = __shfl_up(c2[j].w, 1);
        float r2n = __shfl_down(c2[j].x, 1);
        float b0  = __shfl(c2[j].x, 0);          // element 256
        float a63 = __shfl(c1[j].w, 63);         // element 255
        float l1 = (lane == 0)  ? 0.f : l1n;     // true left image edge
        float r1 = (lane == 63) ? b0  : r1n;     // seam between halves
        float l2 = (lane == 0)  ? a63 : l2n;     // seam between halves
        float r2 = (lane == 63) ? 0.f : r2n;     // true right image edge
#pragma unroll
        for (int t = 0; t < 3; ++t) {
            const int i = j - t;
            if (i >= 0 && i < RR) {
                const float kl = k[t * 3 + 0];
                const float kc = k[t * 3 + 1];
                const float kr = k[t * 3 + 2];
                acc1[i].x = fmaf(kl, l1,      fmaf(kc, c1[j].x, fmaf(kr, c1[j].y, acc1[i].x)));
                acc1[i].y = fmaf(kl, c1[j].x, fmaf(kc, c1[j].y, fmaf(kr, c1[j].z, acc1[i].y)));
                acc1[i].z = fmaf(kl, c1[j].y, fmaf(kc, c1[j].z, fmaf(kr, c1[j].w, acc1[i].z)));
                acc1[i].w = fmaf(kl, c1[j].z, fmaf(kc, c1[j].w, fmaf(kr, r1,      acc1[i].w)));
                acc2[i].x = fmaf(kl, l2,      fmaf(kc, c2[j].x, fmaf(kr, c2[j].y, acc2[i].x)));
                acc2[i].y = fmaf(kl, c2[j].x, fmaf(kc, c2[j].y, fmaf(kr, c2[j].z, acc2[i].y)));
                acc2[i].z = fmaf(kl, c2[j].y, fmaf(kc, c2[j].z, fmaf(kr, c2[j].w, acc2[i].z)));
                acc2[i].w = fmaf(kl, c2[j].z, fmaf(kc, c2[j].w, fmaf(kr, r2,      acc2[i].w)));
            }
        }
    }

#pragma unroll
    for (int i = 0; i < RR; ++i) {
        float* rowo = outp + (size_t)(y0 + i) * WW;
        vfloat4 v1 = { acc1[i].x, acc1[i].y, acc1[i].z, acc1[i].w };
        vfloat4 v2 = { acc2[i].x, acc2[i].y, acc2[i].z, acc2[i].w };
        __builtin_nontemporal_store(v1, (vfloat4*)rowo + lane);
        __builtin_nontemporal_store(v2, (vfloat4*)rowo + lane + 64);
    }
}

extern "C" void kernel_launch(void* const* d_in, const int* in_sizes, int n_in,
                              void* d_out, int out_size, void* d_ws, size_t ws_size,
                              hipStream_t stream) {
    const float* in   = (const float*)d_in[0];   // [64,1,512,512]
    const float* wgt  = (const float*)d_in[1];   // [1,9]
    const float* wfac = (const float*)d_in[2];   // [1,1]
    float* out = (float*)d_out;                  // [1,64,1,512,512]

    const int total = BB * (HH / RR) * 64;       // 524,288 threads (8192 waves)
    const int block = 256;
    const int grid  = total / block;             // 2048
    gauss3x3_kernel<<<grid, block, 0, stream>>>(in, wgt, wfac, out);
}